// Round 16
// baseline (132.648 us; speedup 1.0000x reference)
//
#include <hip/hip_runtime.h>
#include <cstddef>

#define NB 64
#define NQ 64
#define NK 8192
#define ND 64
#define KPB 256            // pass A: k per block (4 waves x 64 k)
#define KSL 512            // k_pv: k per block (4 half-tiles of 128)
#define NSLICE (NK / KSL)  // 16 partial slices per b

typedef __attribute__((ext_vector_type(8))) short short8_t;
typedef __attribute__((ext_vector_type(8))) unsigned short ushort8_t;
typedef __attribute__((ext_vector_type(4))) unsigned short ushort4_t;
typedef __attribute__((ext_vector_type(4))) float float4_t;

static __device__ __forceinline__ unsigned short f2bf(float f) {
    unsigned b = __float_as_uint(f);
    b += 0x7FFFu + ((b >> 16) & 1u);          // RNE
    return (unsigned short)(b >> 16);
}
static __device__ __forceinline__ float bf2f(unsigned short u) {
    return __uint_as_float(((unsigned)u) << 16);
}
static __device__ __forceinline__ void split8(const float* f, short8_t& hi, short8_t& lo) {
#pragma unroll
    for (int j = 0; j < 8; ++j) {
        const unsigned u = __float_as_uint(f[j]);
        hi[j] = (short)(u >> 16);
        const float lof = f[j] - __uint_as_float(u & 0xFFFF0000u);
        lo[j] = (short)(__float_as_uint(lof) >> 16);
    }
}

// ---------------------------------------------------------------------------
// Pass A (round-13 proven, unchanged): MFMA QK^T (bf16 hi/lo 3-term split) +
// inverted softmax without max subtraction (logits ~ N(0,1); max cancels
// algebraically). K double-buffered two subtiles deep. Stores UNNORMALIZED
// bf16 p to ws, pre-swizzled within each 128-k half (16B slot ^= row&7);
// rowsum accumulated from the ROUNDED values.
// ---------------------------------------------------------------------------
__global__ __launch_bounds__(256, 3) void k_qk_p(
    const float* __restrict__ query,
    const float* __restrict__ key,
    unsigned short* __restrict__ pstore,
    float* __restrict__ rowsum)
{
    __shared__ alignas(16) unsigned short SH[64 * 264];  // Q frags, then p tile
    unsigned short* Qhi = SH;
    unsigned short* Qlo = SH + 64 * 72;

    const int tid  = threadIdx.x;
    const int b    = blockIdx.y;
    const int k0   = blockIdx.x * KPB;
    const int lane = tid & 63;
    const int w    = tid >> 6;
    const int lq   = lane & 15;
    const int lg   = lane >> 4;

    const float* krb = key + ((size_t)b * NK + k0 + w * 64 + lq) * ND + lg * 8;

    float kfA[16], kfB[16];
#define LOADK(KF, S)                                                           \
    {                                                                          \
        const float* kr = krb + (size_t)(S) * 16 * ND;                         \
        *reinterpret_cast<float4*>(KF)      = *reinterpret_cast<const float4*>(kr);      \
        *reinterpret_cast<float4*>(KF + 4)  = *reinterpret_cast<const float4*>(kr + 4);  \
        *reinterpret_cast<float4*>(KF + 8)  = *reinterpret_cast<const float4*>(kr + 32); \
        *reinterpret_cast<float4*>(KF + 12) = *reinterpret_cast<const float4*>(kr + 36); \
    }

    LOADK(kfA, 0);
    LOADK(kfB, 1);

    {
        const float* qb = query + (size_t)b * NQ * ND;
#pragma unroll
        for (int i = 0; i < 2; ++i) {
            const int o  = tid + 256 * i;
            const int q  = o >> 3;
            const int d0 = (o & 7) * 8;
            float f[8];
            *reinterpret_cast<float4*>(f)     = *reinterpret_cast<const float4*>(qb + q * ND + d0);
            *reinterpret_cast<float4*>(f + 4) = *reinterpret_cast<const float4*>(qb + q * ND + d0 + 4);
            short8_t h, l8;
            split8(f, h, l8);
            const int n    = q >> 4;
            const int l    = (q & 15) | (((d0 >> 3) & 3) << 4);
            const int dh   = d0 >> 5;
            const int base = l * 72 + n * 16 + dh * 8;
            *reinterpret_cast<short8_t*>(&Qhi[base]) = h;
            *reinterpret_cast<short8_t*>(&Qlo[base]) = l8;
        }
    }
    __syncthreads();

    short8_t bhi[4][2], blo[4][2];
#pragma unroll
    for (int n = 0; n < 4; ++n)
#pragma unroll
        for (int dh = 0; dh < 2; ++dh) {
            const int base = lane * 72 + n * 16 + dh * 8;
            bhi[n][dh] = *reinterpret_cast<const short8_t*>(&Qhi[base]);
            blo[n][dh] = *reinterpret_cast<const short8_t*>(&Qlo[base]);
        }
    __syncthreads();                       // Q frags in regs -> SH reusable

    unsigned short* pL = SH;               // p tile [64 q][264 pitch]
    float rsacc[4] = {0.f, 0.f, 0.f, 0.f};

#define DO_SUBTILE(S, KF, PRE)                                                 \
    {                                                                          \
        short8_t ahi[2], alo[2];                                               \
        split8(KF, ahi[0], alo[0]);                                            \
        split8(KF + 8, ahi[1], alo[1]);                                        \
        if ((PRE) < 4) LOADK(KF, PRE);                                         \
        float4_t acc[4];                                                       \
        _Pragma("unroll")                                                      \
        for (int n = 0; n < 4; ++n) acc[n] = (float4_t){0.f, 0.f, 0.f, 0.f};   \
        _Pragma("unroll")                                                      \
        for (int n = 0; n < 4; ++n)                                            \
            _Pragma("unroll")                                                  \
            for (int dh = 0; dh < 2; ++dh) {                                   \
                acc[n] = __builtin_amdgcn_mfma_f32_16x16x32_bf16(ahi[dh], bhi[n][dh], acc[n], 0, 0, 0); \
                acc[n] = __builtin_amdgcn_mfma_f32_16x16x32_bf16(ahi[dh], blo[n][dh], acc[n], 0, 0, 0); \
                acc[n] = __builtin_amdgcn_mfma_f32_16x16x32_bf16(alo[dh], bhi[n][dh], acc[n], 0, 0, 0); \
            }                                                                  \
        float z[4] = {0.f, 0.f, 0.f, 0.f};                                     \
        _Pragma("unroll")                                                      \
        for (int n = 0; n < 4; ++n)                                            \
            _Pragma("unroll")                                                  \
            for (int r = 0; r < 4; ++r) {                                      \
                acc[n][r] = __expf(acc[n][r] * 0.125f);                        \
                z[r] += acc[n][r];                                             \
            }                                                                  \
        _Pragma("unroll")                                                      \
        for (int r = 0; r < 4; ++r) {                                          \
            z[r] += __shfl_xor(z[r], 1, 64);                                   \
            z[r] += __shfl_xor(z[r], 2, 64);                                   \
            z[r] += __shfl_xor(z[r], 4, 64);                                   \
            z[r] += __shfl_xor(z[r], 8, 64);                                   \
            z[r] = 1.f / z[r];                                                 \
        }                                                                      \
        _Pragma("unroll")                                                      \
        for (int n = 0; n < 4; ++n) {                                          \
            ushort4_t u;                                                       \
            float rs = 0.f;                                                    \
            _Pragma("unroll")                                                  \
            for (int r = 0; r < 4; ++r) {                                      \
                u[r] = f2bf(acc[n][r] * z[r]);                                 \
                rs += bf2f(u[r]);                                              \
            }                                                                  \
            *reinterpret_cast<ushort4_t*>(                                     \
                &pL[(16 * n + lq) * 264 + w * 64 + (S) * 16 + lg * 4]) = u;    \
            rs += __shfl_xor(rs, 16, 64);                                      \
            rs += __shfl_xor(rs, 32, 64);                                      \
            rsacc[n] += rs;                                                    \
        }                                                                      \
    }

    DO_SUBTILE(0, kfA, 2);
    DO_SUBTILE(1, kfB, 3);
    DO_SUBTILE(2, kfA, 4);
    DO_SUBTILE(3, kfB, 4);
#undef DO_SUBTILE
#undef LOADK

    if (lg == 0) {
#pragma unroll
        for (int n = 0; n < 4; ++n)
            atomicAdd(&rowsum[b * NQ + lq + 16 * n], rsacc[n]);
    }
    __syncthreads();   // pL complete

    {
        const int cl = tid & 63;
#pragma unroll
        for (int t = 0; t < 16; ++t) {
            const int row = t * 4 + w;
            const ushort4_t u = *reinterpret_cast<const ushort4_t*>(&pL[row * 264 + cl * 4]);
            const int c      = cl * 4;
            const int half   = c >> 7;
            const int slot   = (c & 127) >> 3;
            const int sub    = (c >> 2) & 1;
            const int sp     = slot ^ (row & 7);
            *reinterpret_cast<ushort4_t*>(pstore +
                ((size_t)(b * NQ + row)) * NK + k0 + half * 128 + sp * 8 + sub * 4) = u;
        }
    }
}

// ---------------------------------------------------------------------------
// k_pv: PV only, on RAW unnormalized bf16 p (invrow folds into reduce).
// Per (b, 512-k tile), 4 half-tiles of 128 k. Stage = pure byte copy of the
// swizzled p image + V bf16 cvt; next half-tile's loads issued between the
// barriers (T14). A-frag LDS reads conflict-free via pass A's pre-swizzle.
// Small register state (rp 32 + rv 32 + oacc 16) -> no spill, 4 blocks/CU.
// ---------------------------------------------------------------------------
template<bool PART>
__global__ __launch_bounds__(256, 4) void k_pv(
    const unsigned short* __restrict__ psrc,
    const float* __restrict__ value,
    float* __restrict__ dst)     // partials if PART else out (unnormalized)
{
    __shared__ alignas(16) unsigned short pLu[64 * 128];   // raw swizzled p image
    __shared__ alignas(16) unsigned short Vsu[128 * 68];   // [k][d] bf16

    const int tid  = threadIdx.x;
    const int b    = blockIdx.y;
    const int ks   = blockIdx.x;
    const int k0   = ks * KSL;
    const int lane = tid & 63;
    const int w    = tid >> 6;
    const int lq   = lane & 15;
    const int lg   = lane >> 4;

    const unsigned short* pg = psrc + (size_t)b * NQ * NK;
    const float4* vg = reinterpret_cast<const float4*>(value + ((size_t)b * NK + k0) * ND);

    ushort8_t rp[4];
    float4 rv[8];

#define LOADP(HT)                                                              \
    {                                                                          \
        _Pragma("unroll")                                                      \
        for (int i = 0; i < 4; ++i) {                                          \
            const int idx = tid + 256 * i;                                     \
            rp[i] = *reinterpret_cast<const ushort8_t*>(                       \
                &pg[(size_t)(idx >> 4) * NK + k0 + (HT) * 128 + (idx & 15) * 8]); \
        }                                                                      \
    }
#define LOADV(HT)                                                              \
    {                                                                          \
        _Pragma("unroll")                                                      \
        for (int i = 0; i < 8; ++i) rv[i] = vg[(HT) * 2048 + tid + 256 * i];   \
    }

    LOADP(0);
    LOADV(0);

    float4_t oacc[4];
#pragma unroll
    for (int n = 0; n < 4; ++n) oacc[n] = (float4_t){0.f, 0.f, 0.f, 0.f};

#pragma unroll 1
    for (int ht = 0; ht < 4; ++ht) {
        __syncthreads();   // prev PV reads done

        // stage: pure copy of p image + V cvt to bf16
#pragma unroll
        for (int i = 0; i < 4; ++i)
            *reinterpret_cast<ushort8_t*>(&pLu[(tid + 256 * i) * 8]) = rp[i];
#pragma unroll
        for (int i = 0; i < 8; ++i) {
            const int idx = tid + 256 * i;
            ushort4_t v4;
            v4[0] = f2bf(rv[i].x); v4[1] = f2bf(rv[i].y);
            v4[2] = f2bf(rv[i].z); v4[3] = f2bf(rv[i].w);
            *reinterpret_cast<ushort4_t*>(&Vsu[(idx >> 4) * 68 + (idx & 15) * 4]) = v4;
        }

        if (ht < 3) {      // T14: next half-tile's loads fly under PV
            LOADP(ht + 1);
            LOADV(ht + 1);
        }
        __syncthreads();   // LDS ready

        // PV via MFMA: wave w owns d strip [16w,16w+16)
#pragma unroll
        for (int h = 0; h < 4; ++h) {
            short8_t vb;
#pragma unroll
            for (int j = 0; j < 8; ++j)
                vb[j] = (short)Vsu[(h * 32 + lg * 8 + j) * 68 + 16 * w + lq];
#pragma unroll
            for (int n = 0; n < 4; ++n) {
                const short8_t pa = *reinterpret_cast<const short8_t*>(
                    &pLu[(16 * n + lq) * 128 + (((h * 4 + lg) ^ (lq & 7)) * 8)]);
                oacc[n] = __builtin_amdgcn_mfma_f32_16x16x32_bf16(pa, vb, oacc[n], 0, 0, 0);
            }
        }
    }
#undef LOADP
#undef LOADV

    // epilogue: UNNORMALIZED; D row q = 16n+4lg+r, col d = 16w+lq
    if (PART) {
        float* pb = dst + ((size_t)(b * NSLICE + ks)) * (NQ * ND);
#pragma unroll
        for (int n = 0; n < 4; ++n)
#pragma unroll
            for (int r = 0; r < 4; ++r)
                pb[(16 * n + 4 * lg + r) * ND + 16 * w + lq] = oacc[n][r];
    } else {
#pragma unroll
        for (int n = 0; n < 4; ++n)
#pragma unroll
            for (int r = 0; r < 4; ++r)
                atomicAdd(dst + ((size_t)(b * NQ + 16 * n + 4 * lg + r)) * ND + 16 * w + lq,
                          oacc[n][r]);
    }
}

// ---------------------------------------------------------------------------
// k_scale: barrier-free streaming. attn[b,q,k] = bf2f(p_swz) * invrow with
// XOR de-swizzle on the write side (XOR maps aligned 64B pairs to aligned
// pairs -> sector coalescing preserved). One wave per q-row.
// ---------------------------------------------------------------------------
__global__ __launch_bounds__(256) void k_scale(
    const unsigned short* __restrict__ psrc,
    const float* __restrict__ rowsum,
    float* __restrict__ attn)
{
    const int b   = blockIdx.y;
    const int row = blockIdx.x * 4 + (threadIdx.x >> 6);
    const int cl  = threadIdx.x & 63;

    const float iv = 1.f / (rowsum[b * NQ + row] + 1e-8f);
    const unsigned short* pr = psrc + ((size_t)(b * NQ + row)) * NK;
    float* ar = attn + ((size_t)(b * NQ + row)) * NK;
    const int rx = row & 7;

#pragma unroll
    for (int it = 0; it < 16; ++it) {
        const int idx  = it * 64 + cl;            // 16B slot index 0..1023
        const ushort8_t u = *reinterpret_cast<const ushort8_t*>(&pr[idx * 8]);
        const int half = idx >> 4;
        const int sp   = idx & 15;                // physical slot
        const int slog = sp ^ rx;                 // logical slot
        float f[8];
#pragma unroll
        for (int j = 0; j < 8; ++j) f[j] = bf2f(u[j]) * iv;
        float* dp = ar + half * 128 + slog * 8;
        *reinterpret_cast<float4*>(dp)     = *reinterpret_cast<float4*>(f);
        *reinterpret_cast<float4*>(dp + 4) = *reinterpret_cast<float4*>(f + 4);
    }
}

// ---------------------------------------------------------------------------
// Reduce: out[b,q,d] = (sum over 16 slices) * 1/(rowsum+eps).
// ---------------------------------------------------------------------------
__global__ __launch_bounds__(256) void k_reduce_out(
    const float* __restrict__ partials,
    const float* __restrict__ rowsum,
    float* __restrict__ out)
{
    const int b   = blockIdx.y;
    const int idx = blockIdx.x * 256 + threadIdx.x;    // float4 idx 0..1023
    const int q   = idx >> 4;
    const float iv = 1.f / (rowsum[b * NQ + q] + 1e-8f);
    const float4* pb = reinterpret_cast<const float4*>(partials + (size_t)b * NSLICE * NQ * ND);
    float4 sum = make_float4(0.f, 0.f, 0.f, 0.f);
#pragma unroll
    for (int s = 0; s < NSLICE; ++s) {
        const float4 v = pb[(size_t)s * (NQ * ND / 4) + idx];
        sum.x += v.x; sum.y += v.y; sum.z += v.z; sum.w += v.w;
    }
    sum.x *= iv; sum.y *= iv; sum.z *= iv; sum.w *= iv;
    reinterpret_cast<float4*>(out + (size_t)b * NQ * ND)[idx] = sum;
}

// Fallback normalize (atomic path): out *= 1/(rowsum+eps)
__global__ __launch_bounds__(256) void k_norm_out(
    const float* __restrict__ rowsum,
    float* __restrict__ out)
{
    const int b   = blockIdx.y;
    const int idx = blockIdx.x * 256 + threadIdx.x;
    const int q   = idx >> 4;
    const float iv = 1.f / (rowsum[b * NQ + q] + 1e-8f);
    float4* op = reinterpret_cast<float4*>(out + (size_t)b * NQ * ND) + idx;
    float4 v = *op;
    v.x *= iv; v.y *= iv; v.z *= iv; v.w *= iv;
    *op = v;
}

extern "C" void kernel_launch(void* const* d_in, const int* in_sizes, int n_in,
                              void* d_out, int out_size, void* d_ws, size_t ws_size,
                              hipStream_t stream) {
    const float* query = (const float*)d_in[0];
    const float* key   = (const float*)d_in[1];
    const float* value = (const float*)d_in[2];

    float* out  = (float*)d_out;                        // [B,Q,D]
    float* attn = (float*)d_out + (size_t)NB * NQ * ND; // [B,Q,K]

    const size_t PB_BYTES   = (size_t)NB * NQ * NK * sizeof(unsigned short); // 64 MiB
    const size_t PART_BYTES = (size_t)NB * NSLICE * NQ * ND * sizeof(float); // 16 MiB

    float* rowsum = (float*)d_ws;                               // 16 KB pad
    unsigned short* pbuf = (unsigned short*)((char*)d_ws + 16384);
    float* partials = (float*)((char*)d_ws + 16384 + PB_BYTES);
    const bool part = ws_size >= 16384 + PB_BYTES + PART_BYTES;

    hipMemsetAsync(rowsum, 0, (size_t)NB * NQ * sizeof(float), stream);
    if (!part)
        hipMemsetAsync(out, 0, (size_t)NB * NQ * ND * sizeof(float), stream);

    dim3 gA(NK / KPB, NB);
    k_qk_p<<<gA, 256, 0, stream>>>(query, key, pbuf, rowsum);

    dim3 gB(NK / KSL, NB);
    if (part) {
        k_pv<true><<<gB, 256, 0, stream>>>(pbuf, value, partials);
        k_scale<<<dim3(NQ / 4, NB), 256, 0, stream>>>(pbuf, rowsum, attn);
        k_reduce_out<<<dim3(4, NB), 256, 0, stream>>>(partials, rowsum, out);
    } else {
        k_pv<false><<<gB, 256, 0, stream>>>(pbuf, value, out);
        k_scale<<<dim3(NQ / 4, NB), 256, 0, stream>>>(pbuf, rowsum, attn);
        k_norm_out<<<dim3(4, NB), 256, 0, stream>>>(rowsum, out);
    }
}

// Round 17
// 120.110 us; speedup vs baseline: 1.1044x; 1.1044x over previous
//
#include <hip/hip_runtime.h>
#include <cstddef>

#define NB 64
#define NQ 64
#define NK 8192
#define ND 64
#define KPB 256            // pass A: k per block (4 waves x 64 k)
#define KSL 512            // pass B: k per block (4 half-tiles of 128)
#define NSLICE (NK / KSL)  // 16 partial slices per b

typedef __attribute__((ext_vector_type(8))) short short8_t;
typedef __attribute__((ext_vector_type(8))) unsigned short ushort8_t;
typedef __attribute__((ext_vector_type(4))) unsigned short ushort4_t;
typedef __attribute__((ext_vector_type(4))) float float4_t;

static __device__ __forceinline__ unsigned short f2bf(float f) {
    unsigned b = __float_as_uint(f);
    b += 0x7FFFu + ((b >> 16) & 1u);          // RNE
    return (unsigned short)(b >> 16);
}
static __device__ __forceinline__ float bf2f(unsigned short u) {
    return __uint_as_float(((unsigned)u) << 16);
}
static __device__ __forceinline__ void split8(const float* f, short8_t& hi, short8_t& lo) {
#pragma unroll
    for (int j = 0; j < 8; ++j) {
        const unsigned u = __float_as_uint(f[j]);
        hi[j] = (short)(u >> 16);
        const float lof = f[j] - __uint_as_float(u & 0xFFFF0000u);
        lo[j] = (short)(__float_as_uint(lof) >> 16);
    }
}

// ---------------------------------------------------------------------------
// Pass A (round-13 proven, unchanged): MFMA QK^T (bf16 hi/lo 3-term split) +
// inverted softmax without max subtraction (logits ~ N(0,1); max cancels
// algebraically). K double-buffered two subtiles deep. Stores UNNORMALIZED
// bf16 p to ws, pre-swizzled within each 128-k half (16B slot ^= row&7);
// rowsum accumulated from the ROUNDED values.
// ---------------------------------------------------------------------------
__global__ __launch_bounds__(256, 3) void k_qk_p(
    const float* __restrict__ query,
    const float* __restrict__ key,
    unsigned short* __restrict__ pstore,
    float* __restrict__ rowsum)
{
    __shared__ alignas(16) unsigned short SH[64 * 264];  // Q frags, then p tile
    unsigned short* Qhi = SH;
    unsigned short* Qlo = SH + 64 * 72;

    const int tid  = threadIdx.x;
    const int b    = blockIdx.y;
    const int k0   = blockIdx.x * KPB;
    const int lane = tid & 63;
    const int w    = tid >> 6;
    const int lq   = lane & 15;
    const int lg   = lane >> 4;

    const float* krb = key + ((size_t)b * NK + k0 + w * 64 + lq) * ND + lg * 8;

    float kfA[16], kfB[16];
#define LOADK(KF, S)                                                           \
    {                                                                          \
        const float* kr = krb + (size_t)(S) * 16 * ND;                         \
        *reinterpret_cast<float4*>(KF)      = *reinterpret_cast<const float4*>(kr);      \
        *reinterpret_cast<float4*>(KF + 4)  = *reinterpret_cast<const float4*>(kr + 4);  \
        *reinterpret_cast<float4*>(KF + 8)  = *reinterpret_cast<const float4*>(kr + 32); \
        *reinterpret_cast<float4*>(KF + 12) = *reinterpret_cast<const float4*>(kr + 36); \
    }

    LOADK(kfA, 0);
    LOADK(kfB, 1);

    {
        const float* qb = query + (size_t)b * NQ * ND;
#pragma unroll
        for (int i = 0; i < 2; ++i) {
            const int o  = tid + 256 * i;
            const int q  = o >> 3;
            const int d0 = (o & 7) * 8;
            float f[8];
            *reinterpret_cast<float4*>(f)     = *reinterpret_cast<const float4*>(qb + q * ND + d0);
            *reinterpret_cast<float4*>(f + 4) = *reinterpret_cast<const float4*>(qb + q * ND + d0 + 4);
            short8_t h, l8;
            split8(f, h, l8);
            const int n    = q >> 4;
            const int l    = (q & 15) | (((d0 >> 3) & 3) << 4);
            const int dh   = d0 >> 5;
            const int base = l * 72 + n * 16 + dh * 8;
            *reinterpret_cast<short8_t*>(&Qhi[base]) = h;
            *reinterpret_cast<short8_t*>(&Qlo[base]) = l8;
        }
    }
    __syncthreads();

    short8_t bhi[4][2], blo[4][2];
#pragma unroll
    for (int n = 0; n < 4; ++n)
#pragma unroll
        for (int dh = 0; dh < 2; ++dh) {
            const int base = lane * 72 + n * 16 + dh * 8;
            bhi[n][dh] = *reinterpret_cast<const short8_t*>(&Qhi[base]);
            blo[n][dh] = *reinterpret_cast<const short8_t*>(&Qlo[base]);
        }
    __syncthreads();                       // Q frags in regs -> SH reusable

    unsigned short* pL = SH;               // p tile [64 q][264 pitch]
    float rsacc[4] = {0.f, 0.f, 0.f, 0.f};

#define DO_SUBTILE(S, KF, PRE)                                                 \
    {                                                                          \
        short8_t ahi[2], alo[2];                                               \
        split8(KF, ahi[0], alo[0]);                                            \
        split8(KF + 8, ahi[1], alo[1]);                                        \
        if ((PRE) < 4) LOADK(KF, PRE);                                         \
        float4_t acc[4];                                                       \
        _Pragma("unroll")                                                      \
        for (int n = 0; n < 4; ++n) acc[n] = (float4_t){0.f, 0.f, 0.f, 0.f};   \
        _Pragma("unroll")                                                      \
        for (int n = 0; n < 4; ++n)                                            \
            _Pragma("unroll")                                                  \
            for (int dh = 0; dh < 2; ++dh) {                                   \
                acc[n] = __builtin_amdgcn_mfma_f32_16x16x32_bf16(ahi[dh], bhi[n][dh], acc[n], 0, 0, 0); \
                acc[n] = __builtin_amdgcn_mfma_f32_16x16x32_bf16(ahi[dh], blo[n][dh], acc[n], 0, 0, 0); \
                acc[n] = __builtin_amdgcn_mfma_f32_16x16x32_bf16(alo[dh], bhi[n][dh], acc[n], 0, 0, 0); \
            }                                                                  \
        float z[4] = {0.f, 0.f, 0.f, 0.f};                                     \
        _Pragma("unroll")                                                      \
        for (int n = 0; n < 4; ++n)                                            \
            _Pragma("unroll")                                                  \
            for (int r = 0; r < 4; ++r) {                                      \
                acc[n][r] = __expf(acc[n][r] * 0.125f);                        \
                z[r] += acc[n][r];                                             \
            }                                                                  \
        _Pragma("unroll")                                                      \
        for (int r = 0; r < 4; ++r) {                                          \
            z[r] += __shfl_xor(z[r], 1, 64);                                   \
            z[r] += __shfl_xor(z[r], 2, 64);                                   \
            z[r] += __shfl_xor(z[r], 4, 64);                                   \
            z[r] += __shfl_xor(z[r], 8, 64);                                   \
            z[r] = 1.f / z[r];                                                 \
        }                                                                      \
        _Pragma("unroll")                                                      \
        for (int n = 0; n < 4; ++n) {                                          \
            ushort4_t u;                                                       \
            float rs = 0.f;                                                    \
            _Pragma("unroll")                                                  \
            for (int r = 0; r < 4; ++r) {                                      \
                u[r] = f2bf(acc[n][r] * z[r]);                                 \
                rs += bf2f(u[r]);                                              \
            }                                                                  \
            *reinterpret_cast<ushort4_t*>(                                     \
                &pL[(16 * n + lq) * 264 + w * 64 + (S) * 16 + lg * 4]) = u;    \
            rs += __shfl_xor(rs, 16, 64);                                      \
            rs += __shfl_xor(rs, 32, 64);                                      \
            rsacc[n] += rs;                                                    \
        }                                                                      \
    }

    DO_SUBTILE(0, kfA, 2);
    DO_SUBTILE(1, kfB, 3);
    DO_SUBTILE(2, kfA, 4);
    DO_SUBTILE(3, kfB, 4);
#undef DO_SUBTILE
#undef LOADK

    if (lg == 0) {
#pragma unroll
        for (int n = 0; n < 4; ++n)
            atomicAdd(&rowsum[b * NQ + lq + 16 * n], rsacc[n]);
    }
    __syncthreads();   // pL complete

    {
        const int cl = tid & 63;
#pragma unroll
        for (int t = 0; t < 16; ++t) {
            const int row = t * 4 + w;
            const ushort4_t u = *reinterpret_cast<const ushort4_t*>(&pL[row * 264 + cl * 4]);
            const int c      = cl * 4;
            const int half   = c >> 7;
            const int slot   = (c & 127) >> 3;
            const int sub    = (c >> 2) & 1;
            const int sp     = slot ^ (row & 7);
            *reinterpret_cast<ushort4_t*>(pstore +
                ((size_t)(b * NQ + row)) * NK + k0 + half * 128 + sp * 8 + sub * 4) = u;
        }
    }
}

// ---------------------------------------------------------------------------
// Pass B: per (b, 512-k tile), 4 half-tiles of 128 k.
//  - STAGE = pure copy (raw swizzled bf16 p -> pLu; V cvt -> Vsu). PV runs
//    on UNNORMALIZED p; invrow folds into the reduce.
//  - prefetch for the next half-tile issues AFTER the stage-end barrier, so
//    the loads retire under the PV phase (round-13 issued them before the
//    barrier, which drains vmcnt(0) -> zero PV overlap).
//  - attn (scaled fp32) stores issue early in the PV phase, sourced from a
//    pLu LDS re-read (no extra live registers), retiring under the MFMAs.
// LDS: pLu 16KB + Vsu 17KB -> 4 blocks/CU. rp/rv single-buffered.
// ---------------------------------------------------------------------------
template<bool PART>
__global__ __launch_bounds__(256, 4) void k_scale_pv(
    const unsigned short* __restrict__ psrc,
    const float* __restrict__ value,
    const float* __restrict__ rowsum,
    float* __restrict__ attn,
    float* __restrict__ dst)     // partials if PART else out (unnormalized)
{
    __shared__ alignas(16) unsigned short pLu[64 * 128];   // raw swizzled p image
    __shared__ alignas(16) unsigned short Vsu[128 * 68];   // [k][d] bf16
    __shared__ float rsL[NQ];

    const int tid  = threadIdx.x;
    const int b    = blockIdx.y;
    const int ks   = blockIdx.x;
    const int k0   = ks * KSL;
    const int lane = tid & 63;
    const int w    = tid >> 6;
    const int lq   = lane & 15;
    const int lg   = lane >> 4;

    if (tid < NQ) rsL[tid] = 1.f / (rowsum[b * NQ + tid] + 1e-8f);

    const unsigned short* pg = psrc + (size_t)b * NQ * NK;
    const float4* vg = reinterpret_cast<const float4*>(value + ((size_t)b * NK + k0) * ND);

    ushort8_t rp[4];
    float4 rv[8];

#define LOADP(HT)                                                              \
    {                                                                          \
        _Pragma("unroll")                                                      \
        for (int i = 0; i < 4; ++i) {                                          \
            const int idx = tid + 256 * i;                                     \
            rp[i] = *reinterpret_cast<const ushort8_t*>(                       \
                &pg[(size_t)(idx >> 4) * NK + k0 + (HT) * 128 + (idx & 15) * 8]); \
        }                                                                      \
    }
#define LOADV(HT)                                                              \
    {                                                                          \
        _Pragma("unroll")                                                      \
        for (int i = 0; i < 8; ++i) rv[i] = vg[(HT) * 2048 + tid + 256 * i];   \
    }

    LOADP(0);
    LOADV(0);
    __syncthreads();            // rsL visible

    float ivr[4];
#pragma unroll
    for (int i = 0; i < 4; ++i) ivr[i] = rsL[(tid + 256 * i) >> 4];

    float4_t oacc[4];
#pragma unroll
    for (int n = 0; n < 4; ++n) oacc[n] = (float4_t){0.f, 0.f, 0.f, 0.f};

#pragma unroll 1
    for (int ht = 0; ht < 4; ++ht) {
        // ---- STAGE: pure copy (consumes rp, rv)
#pragma unroll
        for (int i = 0; i < 4; ++i)
            *reinterpret_cast<ushort8_t*>(&pLu[(tid + 256 * i) * 8]) = rp[i];
#pragma unroll
        for (int i = 0; i < 8; ++i) {
            const int idx = tid + 256 * i;
            ushort4_t v4;
            v4[0] = f2bf(rv[i].x); v4[1] = f2bf(rv[i].y);
            v4[2] = f2bf(rv[i].z); v4[3] = f2bf(rv[i].w);
            *reinterpret_cast<ushort4_t*>(&Vsu[(idx >> 4) * 68 + (idx & 15) * 4]) = v4;
        }
        __syncthreads();   // LDS ready (also drains prev iter's attn stores)

        // ---- prefetch next half-tile AFTER the barrier: flies under PV
        if (ht < 3) {
            LOADP(ht + 1);
            LOADV(ht + 1);
        }

        // ---- attn stores early in PV phase (from pLu re-read; retire under MFMAs)
#pragma unroll
        for (int i = 0; i < 4; ++i) {
            const int idx  = tid + 256 * i;
            const int row  = idx >> 4;
            const int slog = (idx & 15) ^ (row & 7);
            const ushort8_t u = *reinterpret_cast<const ushort8_t*>(&pLu[idx * 8]);
            float f[8];
#pragma unroll
            for (int j = 0; j < 8; ++j) f[j] = bf2f(u[j]) * ivr[i];
            float* ap = attn + ((size_t)(b * NQ + row)) * NK + k0 + ht * 128 + slog * 8;
            *reinterpret_cast<float4*>(ap)     = *reinterpret_cast<float4*>(f);
            *reinterpret_cast<float4*>(ap + 4) = *reinterpret_cast<float4*>(f + 4);
        }

        // ---- PV via MFMA: wave w owns d strip [16w,16w+16)
#pragma unroll
        for (int h = 0; h < 4; ++h) {
            short8_t vb;
#pragma unroll
            for (int j = 0; j < 8; ++j)
                vb[j] = (short)Vsu[(h * 32 + lg * 8 + j) * 68 + 16 * w + lq];
#pragma unroll
            for (int n = 0; n < 4; ++n) {
                const short8_t pa = *reinterpret_cast<const short8_t*>(
                    &pLu[(16 * n + lq) * 128 + (((h * 4 + lg) ^ (lq & 7)) * 8)]);
                oacc[n] = __builtin_amdgcn_mfma_f32_16x16x32_bf16(pa, vb, oacc[n], 0, 0, 0);
            }
        }
        __syncthreads();   // PV reads done; drains this iter's loads + stores
    }
#undef LOADP
#undef LOADV

    // ---- epilogue: UNNORMALIZED partials; row q = 16n+4lg+r, col d = 16w+lq
    if (PART) {
        float* pb = dst + ((size_t)(b * NSLICE + ks)) * (NQ * ND);
#pragma unroll
        for (int n = 0; n < 4; ++n)
#pragma unroll
            for (int r = 0; r < 4; ++r)
                pb[(16 * n + 4 * lg + r) * ND + 16 * w + lq] = oacc[n][r];
    } else {
#pragma unroll
        for (int n = 0; n < 4; ++n)
#pragma unroll
            for (int r = 0; r < 4; ++r)
                atomicAdd(dst + ((size_t)(b * NQ + 16 * n + 4 * lg + r)) * ND + 16 * w + lq,
                          oacc[n][r]);
    }
}

// ---------------------------------------------------------------------------
// Reduce: out[b,q,d] = (sum over 16 slices) * 1/(rowsum+eps).
// ---------------------------------------------------------------------------
__global__ __launch_bounds__(256) void k_reduce_out(
    const float* __restrict__ partials,
    const float* __restrict__ rowsum,
    float* __restrict__ out)
{
    const int b   = blockIdx.y;
    const int idx = blockIdx.x * 256 + threadIdx.x;    // float4 idx 0..1023
    const int q   = idx >> 4;
    const float iv = 1.f / (rowsum[b * NQ + q] + 1e-8f);
    const float4* pb = reinterpret_cast<const float4*>(partials + (size_t)b * NSLICE * NQ * ND);
    float4 sum = make_float4(0.f, 0.f, 0.f, 0.f);
#pragma unroll
    for (int s = 0; s < NSLICE; ++s) {
        const float4 v = pb[(size_t)s * (NQ * ND / 4) + idx];
        sum.x += v.x; sum.y += v.y; sum.z += v.z; sum.w += v.w;
    }
    sum.x *= iv; sum.y *= iv; sum.z *= iv; sum.w *= iv;
    reinterpret_cast<float4*>(out + (size_t)b * NQ * ND)[idx] = sum;
}

// Fallback normalize (atomic path): out *= 1/(rowsum+eps)
__global__ __launch_bounds__(256) void k_norm_out(
    const float* __restrict__ rowsum,
    float* __restrict__ out)
{
    const int b   = blockIdx.y;
    const int idx = blockIdx.x * 256 + threadIdx.x;
    const int q   = idx >> 4;
    const float iv = 1.f / (rowsum[b * NQ + q] + 1e-8f);
    float4* op = reinterpret_cast<float4*>(out + (size_t)b * NQ * ND) + idx;
    float4 v = *op;
    v.x *= iv; v.y *= iv; v.z *= iv; v.w *= iv;
    *op = v;
}

extern "C" void kernel_launch(void* const* d_in, const int* in_sizes, int n_in,
                              void* d_out, int out_size, void* d_ws, size_t ws_size,
                              hipStream_t stream) {
    const float* query = (const float*)d_in[0];
    const float* key   = (const float*)d_in[1];
    const float* value = (const float*)d_in[2];

    float* out  = (float*)d_out;                        // [B,Q,D]
    float* attn = (float*)d_out + (size_t)NB * NQ * ND; // [B,Q,K]

    const size_t PB_BYTES   = (size_t)NB * NQ * NK * sizeof(unsigned short); // 64 MiB
    const size_t PART_BYTES = (size_t)NB * NSLICE * NQ * ND * sizeof(float); // 16 MiB

    float* rowsum = (float*)d_ws;                               // 16 KB pad
    unsigned short* pbuf = (unsigned short*)((char*)d_ws + 16384);
    float* partials = (float*)((char*)d_ws + 16384 + PB_BYTES);
    const bool part = ws_size >= 16384 + PB_BYTES + PART_BYTES;

    hipMemsetAsync(rowsum, 0, (size_t)NB * NQ * sizeof(float), stream);
    if (!part)
        hipMemsetAsync(out, 0, (size_t)NB * NQ * ND * sizeof(float), stream);

    dim3 gA(NK / KPB, NB);
    k_qk_p<<<gA, 256, 0, stream>>>(query, key, pbuf, rowsum);

    dim3 gB(NK / KSL, NB);
    if (part) {
        k_scale_pv<true><<<gB, 256, 0, stream>>>(pbuf, value, rowsum, attn, partials);
        k_reduce_out<<<dim3(4, NB), 256, 0, stream>>>(partials, rowsum, out);
    } else {
        k_scale_pv<false><<<gB, 256, 0, stream>>>(pbuf, value, rowsum, attn, out);
        k_norm_out<<<dim3(4, NB), 256, 0, stream>>>(rowsum, out);
    }
}

// Round 18
// 118.117 us; speedup vs baseline: 1.1230x; 1.0169x over previous
//
#include <hip/hip_runtime.h>
#include <cstddef>

#define NB 64
#define NQ 64
#define NK 8192
#define ND 64
#define KPB 256            // pass A: k per block (4 waves x 64 k)
#define KSL 512            // pass B: k per block (4 half-tiles of 128)
#define NSLICE (NK / KSL)  // 16 partial slices per b

typedef __attribute__((ext_vector_type(8))) short short8_t;
typedef __attribute__((ext_vector_type(8))) unsigned short ushort8_t;
typedef __attribute__((ext_vector_type(4))) unsigned short ushort4_t;
typedef __attribute__((ext_vector_type(4))) float float4_t;

static __device__ __forceinline__ unsigned short f2bf(float f) {
    unsigned b = __float_as_uint(f);
    b += 0x7FFFu + ((b >> 16) & 1u);          // RNE
    return (unsigned short)(b >> 16);
}
static __device__ __forceinline__ float bf2f(unsigned short u) {
    return __uint_as_float(((unsigned)u) << 16);
}
static __device__ __forceinline__ void split8(const float* f, short8_t& hi, short8_t& lo) {
#pragma unroll
    for (int j = 0; j < 8; ++j) {
        const unsigned u = __float_as_uint(f[j]);
        hi[j] = (short)(u >> 16);
        const float lof = f[j] - __uint_as_float(u & 0xFFFF0000u);
        lo[j] = (short)(__float_as_uint(lof) >> 16);
    }
}

// ---------------------------------------------------------------------------
// Pass A: MFMA QK^T (bf16 hi/lo 3-term split) + inverted softmax without max
// subtraction (logits ~ N(0,1): exp range safe; max cancels algebraically).
// K double-buffered two subtiles deep. Stores UNNORMALIZED bf16 p to ws,
// pre-swizzled within each 128-k half (16B slot ^= row&7); rowsum
// accumulated from the ROUNDED values.
// ---------------------------------------------------------------------------
__global__ __launch_bounds__(256, 3) void k_qk_p(
    const float* __restrict__ query,
    const float* __restrict__ key,
    unsigned short* __restrict__ pstore,
    float* __restrict__ rowsum)
{
    __shared__ alignas(16) unsigned short SH[64 * 264];  // Q frags, then p tile
    unsigned short* Qhi = SH;
    unsigned short* Qlo = SH + 64 * 72;

    const int tid  = threadIdx.x;
    const int b    = blockIdx.y;
    const int k0   = blockIdx.x * KPB;
    const int lane = tid & 63;
    const int w    = tid >> 6;
    const int lq   = lane & 15;
    const int lg   = lane >> 4;

    const float* krb = key + ((size_t)b * NK + k0 + w * 64 + lq) * ND + lg * 8;

    float kfA[16], kfB[16];
#define LOADK(KF, S)                                                           \
    {                                                                          \
        const float* kr = krb + (size_t)(S) * 16 * ND;                         \
        *reinterpret_cast<float4*>(KF)      = *reinterpret_cast<const float4*>(kr);      \
        *reinterpret_cast<float4*>(KF + 4)  = *reinterpret_cast<const float4*>(kr + 4);  \
        *reinterpret_cast<float4*>(KF + 8)  = *reinterpret_cast<const float4*>(kr + 32); \
        *reinterpret_cast<float4*>(KF + 12) = *reinterpret_cast<const float4*>(kr + 36); \
    }

    LOADK(kfA, 0);
    LOADK(kfB, 1);

    {
        const float* qb = query + (size_t)b * NQ * ND;
#pragma unroll
        for (int i = 0; i < 2; ++i) {
            const int o  = tid + 256 * i;
            const int q  = o >> 3;
            const int d0 = (o & 7) * 8;
            float f[8];
            *reinterpret_cast<float4*>(f)     = *reinterpret_cast<const float4*>(qb + q * ND + d0);
            *reinterpret_cast<float4*>(f + 4) = *reinterpret_cast<const float4*>(qb + q * ND + d0 + 4);
            short8_t h, l8;
            split8(f, h, l8);
            const int n    = q >> 4;
            const int l    = (q & 15) | (((d0 >> 3) & 3) << 4);
            const int dh   = d0 >> 5;
            const int base = l * 72 + n * 16 + dh * 8;
            *reinterpret_cast<short8_t*>(&Qhi[base]) = h;
            *reinterpret_cast<short8_t*>(&Qlo[base]) = l8;
        }
    }
    __syncthreads();

    short8_t bhi[4][2], blo[4][2];
#pragma unroll
    for (int n = 0; n < 4; ++n)
#pragma unroll
        for (int dh = 0; dh < 2; ++dh) {
            const int base = lane * 72 + n * 16 + dh * 8;
            bhi[n][dh] = *reinterpret_cast<const short8_t*>(&Qhi[base]);
            blo[n][dh] = *reinterpret_cast<const short8_t*>(&Qlo[base]);
        }
    __syncthreads();                       // Q frags in regs -> SH reusable

    unsigned short* pL = SH;               // p tile [64 q][264 pitch]
    float rsacc[4] = {0.f, 0.f, 0.f, 0.f};

#define DO_SUBTILE(S, KF, PRE)                                                 \
    {                                                                          \
        short8_t ahi[2], alo[2];                                               \
        split8(KF, ahi[0], alo[0]);                                            \
        split8(KF + 8, ahi[1], alo[1]);                                        \
        if ((PRE) < 4) LOADK(KF, PRE);                                         \
        float4_t acc[4];                                                       \
        _Pragma("unroll")                                                      \
        for (int n = 0; n < 4; ++n) acc[n] = (float4_t){0.f, 0.f, 0.f, 0.f};   \
        _Pragma("unroll")                                                      \
        for (int n = 0; n < 4; ++n)                                            \
            _Pragma("unroll")                                                  \
            for (int dh = 0; dh < 2; ++dh) {                                   \
                acc[n] = __builtin_amdgcn_mfma_f32_16x16x32_bf16(ahi[dh], bhi[n][dh], acc[n], 0, 0, 0); \
                acc[n] = __builtin_amdgcn_mfma_f32_16x16x32_bf16(ahi[dh], blo[n][dh], acc[n], 0, 0, 0); \
                acc[n] = __builtin_amdgcn_mfma_f32_16x16x32_bf16(alo[dh], bhi[n][dh], acc[n], 0, 0, 0); \
            }                                                                  \
        float z[4] = {0.f, 0.f, 0.f, 0.f};                                     \
        _Pragma("unroll")                                                      \
        for (int n = 0; n < 4; ++n)                                            \
            _Pragma("unroll")                                                  \
            for (int r = 0; r < 4; ++r) {                                      \
                acc[n][r] = __expf(acc[n][r] * 0.125f);                        \
                z[r] += acc[n][r];                                             \
            }                                                                  \
        _Pragma("unroll")                                                      \
        for (int r = 0; r < 4; ++r) {                                          \
            z[r] += __shfl_xor(z[r], 1, 64);                                   \
            z[r] += __shfl_xor(z[r], 2, 64);                                   \
            z[r] += __shfl_xor(z[r], 4, 64);                                   \
            z[r] += __shfl_xor(z[r], 8, 64);                                   \
            z[r] = 1.f / z[r];                                                 \
        }                                                                      \
        _Pragma("unroll")                                                      \
        for (int n = 0; n < 4; ++n) {                                          \
            ushort4_t u;                                                       \
            float rs = 0.f;                                                    \
            _Pragma("unroll")                                                  \
            for (int r = 0; r < 4; ++r) {                                      \
                u[r] = f2bf(acc[n][r] * z[r]);                                 \
                rs += bf2f(u[r]);                                              \
            }                                                                  \
            *reinterpret_cast<ushort4_t*>(                                     \
                &pL[(16 * n + lq) * 264 + w * 64 + (S) * 16 + lg * 4]) = u;    \
            rs += __shfl_xor(rs, 16, 64);                                      \
            rs += __shfl_xor(rs, 32, 64);                                      \
            rsacc[n] += rs;                                                    \
        }                                                                      \
    }

    DO_SUBTILE(0, kfA, 2);
    DO_SUBTILE(1, kfB, 3);
    DO_SUBTILE(2, kfA, 4);
    DO_SUBTILE(3, kfB, 4);
#undef DO_SUBTILE
#undef LOADK

    if (lg == 0) {
#pragma unroll
        for (int n = 0; n < 4; ++n)
            atomicAdd(&rowsum[b * NQ + lq + 16 * n], rsacc[n]);
    }
    __syncthreads();   // pL complete

    {
        const int cl = tid & 63;
#pragma unroll
        for (int t = 0; t < 16; ++t) {
            const int row = t * 4 + w;
            const ushort4_t u = *reinterpret_cast<const ushort4_t*>(&pL[row * 264 + cl * 4]);
            const int c      = cl * 4;
            const int half   = c >> 7;
            const int slot   = (c & 127) >> 3;
            const int sub    = (c >> 2) & 1;
            const int sp     = slot ^ (row & 7);
            *reinterpret_cast<ushort4_t*>(pstore +
                ((size_t)(b * NQ + row)) * NK + k0 + half * 128 + sp * 8 + sub * 4) = u;
        }
    }
}

// ---------------------------------------------------------------------------
// Pass B (round-10/13 proven): per (b, 512-k tile), 4 half-tiles of 128:
// load swizzled bf16 p (linear, coalesced) + V, scale p by 1/(rowsum+eps),
// write FINAL fp32 attn (col de-swizzled), stage p (linear) + V (bf16) in
// LDS, PV via MFMA; A-frag reads conflict-free via the global pre-swizzle.
// Next half-tile's loads issued before PV. Deterministic partials.
// ---------------------------------------------------------------------------
template<bool PART>
__global__ __launch_bounds__(256, 4) void k_scale_pv(
    const unsigned short* __restrict__ psrc,
    const float* __restrict__ value,
    const float* __restrict__ rowsum,
    float* __restrict__ attn,
    float* __restrict__ dst)     // partials if PART else out
{
    __shared__ alignas(16) unsigned short pLu[64 * 128];   // linear swizzled image
    __shared__ alignas(16) unsigned short Vsu[128 * 68];   // [k][d] bf16
    __shared__ float rsL[NQ];

    const int tid  = threadIdx.x;
    const int b    = blockIdx.y;
    const int ks   = blockIdx.x;
    const int k0   = ks * KSL;
    const int lane = tid & 63;
    const int w    = tid >> 6;
    const int lq   = lane & 15;
    const int lg   = lane >> 4;

    if (tid < NQ) rsL[tid] = 1.f / (rowsum[b * NQ + tid] + 1e-8f);

    const unsigned short* pg = psrc + (size_t)b * NQ * NK;
    const float4* vg = reinterpret_cast<const float4*>(value + ((size_t)b * NK + k0) * ND);

    // prologue: half-tile 0 loads
    ushort8_t rp[4];
    float4 rv[8];
#pragma unroll
    for (int i = 0; i < 4; ++i) {
        const int idx = tid + 256 * i;
        rp[i] = *reinterpret_cast<const ushort8_t*>(
            &pg[(size_t)(idx >> 4) * NK + k0 + (idx & 15) * 8]);
    }
#pragma unroll
    for (int i = 0; i < 8; ++i) rv[i] = vg[tid + 256 * i];

    float4_t oacc[4];
#pragma unroll
    for (int n = 0; n < 4; ++n) oacc[n] = (float4_t){0.f, 0.f, 0.f, 0.f};

#pragma unroll 1
    for (int ht = 0; ht < 4; ++ht) {
        __syncthreads();   // prev PV done (ht=0: rsL visible)

        // ---- consume regs: attn write (de-swizzled col) + pLu/Vsu stage
#pragma unroll
        for (int i = 0; i < 4; ++i) {
            const int idx  = tid + 256 * i;
            const int row  = idx >> 4;
            const int sl   = idx & 15;                 // physical slot
            const int slog = sl ^ (row & 7);           // logical slot
            const float iv = rsL[row];
            float f[8];
            ushort8_t u;
#pragma unroll
            for (int j = 0; j < 8; ++j) {
                f[j] = bf2f(rp[i][j]) * iv;            // FINAL attn value, fp32
                u[j] = f2bf(f[j]);                     // bf16 for PV MFMA
            }
            float* ap = attn + ((size_t)(b * NQ + row)) * NK + k0 + ht * 128 + slog * 8;
            *reinterpret_cast<float4*>(ap)     = *reinterpret_cast<float4*>(f);
            *reinterpret_cast<float4*>(ap + 4) = *reinterpret_cast<float4*>(f + 4);
            *reinterpret_cast<ushort8_t*>(&pLu[idx * 8]) = u;   // linear
        }
#pragma unroll
        for (int i = 0; i < 8; ++i) {
            const int idx = tid + 256 * i;
            ushort4_t v4;
            v4[0] = f2bf(rv[i].x); v4[1] = f2bf(rv[i].y);
            v4[2] = f2bf(rv[i].z); v4[3] = f2bf(rv[i].w);
            *reinterpret_cast<ushort4_t*>(&Vsu[(idx >> 4) * 68 + (idx & 15) * 4]) = v4;
        }

        // ---- issue next half-tile's loads
        if (ht < 3) {
            const int kn = k0 + (ht + 1) * 128;
#pragma unroll
            for (int i = 0; i < 4; ++i) {
                const int idx = tid + 256 * i;
                rp[i] = *reinterpret_cast<const ushort8_t*>(
                    &pg[(size_t)(idx >> 4) * NK + kn + (idx & 15) * 8]);
            }
#pragma unroll
            for (int i = 0; i < 8; ++i)
                rv[i] = vg[(ht + 1) * 2048 + tid + 256 * i];
        }
        __syncthreads();   // LDS ready

        // ---- PV via MFMA: wave w owns d strip [16w,16w+16)
#pragma unroll
        for (int h = 0; h < 4; ++h) {
            short8_t vb;
#pragma unroll
            for (int j = 0; j < 8; ++j)
                vb[j] = (short)Vsu[(h * 32 + lg * 8 + j) * 68 + 16 * w + lq];
#pragma unroll
            for (int n = 0; n < 4; ++n) {
                const short8_t pa = *reinterpret_cast<const short8_t*>(
                    &pLu[(16 * n + lq) * 128 + (((h * 4 + lg) ^ (lq & 7)) * 8)]);
                oacc[n] = __builtin_amdgcn_mfma_f32_16x16x32_bf16(pa, vb, oacc[n], 0, 0, 0);
            }
        }
    }

    // ---- epilogue: D row q = 16n+4lg+r, col d = 16w+lq
    if (PART) {
        float* pb = dst + ((size_t)(b * NSLICE + ks)) * (NQ * ND);
#pragma unroll
        for (int n = 0; n < 4; ++n)
#pragma unroll
            for (int r = 0; r < 4; ++r)
                pb[(16 * n + 4 * lg + r) * ND + 16 * w + lq] = oacc[n][r];
    } else {
#pragma unroll
        for (int n = 0; n < 4; ++n)
#pragma unroll
            for (int r = 0; r < 4; ++r)
                atomicAdd(dst + ((size_t)(b * NQ + 16 * n + 4 * lg + r)) * ND + 16 * w + lq,
                          oacc[n][r]);
    }
}

// ---------------------------------------------------------------------------
// Reduce: out[b,q,d] = sum over 16 slices.
// ---------------------------------------------------------------------------
__global__ __launch_bounds__(256) void k_reduce_out(
    const float* __restrict__ partials,
    float* __restrict__ out)
{
    const int b   = blockIdx.y;
    const int idx = blockIdx.x * 256 + threadIdx.x;    // 0..1023 float4 per b
    const float4* pb = reinterpret_cast<const float4*>(partials + (size_t)b * NSLICE * NQ * ND);
    float4 sum = make_float4(0.f, 0.f, 0.f, 0.f);
#pragma unroll
    for (int s = 0; s < NSLICE; ++s) {
        const float4 v = pb[(size_t)s * (NQ * ND / 4) + idx];
        sum.x += v.x; sum.y += v.y; sum.z += v.z; sum.w += v.w;
    }
    reinterpret_cast<float4*>(out + (size_t)b * NQ * ND)[idx] = sum;
}

extern "C" void kernel_launch(void* const* d_in, const int* in_sizes, int n_in,
                              void* d_out, int out_size, void* d_ws, size_t ws_size,
                              hipStream_t stream) {
    const float* query = (const float*)d_in[0];
    const float* key   = (const float*)d_in[1];
    const float* value = (const float*)d_in[2];

    float* out  = (float*)d_out;                        // [B,Q,D]
    float* attn = (float*)d_out + (size_t)NB * NQ * ND; // [B,Q,K]

    const size_t PB_BYTES   = (size_t)NB * NQ * NK * sizeof(unsigned short); // 64 MiB
    const size_t PART_BYTES = (size_t)NB * NSLICE * NQ * ND * sizeof(float); // 16 MiB

    float* rowsum = (float*)d_ws;                               // 16 KB pad
    unsigned short* pbuf = (unsigned short*)((char*)d_ws + 16384);
    float* partials = (float*)((char*)d_ws + 16384 + PB_BYTES);
    const bool part = ws_size >= 16384 + PB_BYTES + PART_BYTES;

    hipMemsetAsync(rowsum, 0, (size_t)NB * NQ * sizeof(float), stream);
    if (!part)
        hipMemsetAsync(out, 0, (size_t)NB * NQ * ND * sizeof(float), stream);

    dim3 gA(NK / KPB, NB);
    k_qk_p<<<gA, 256, 0, stream>>>(query, key, pbuf, rowsum);

    dim3 gB(NK / KSL, NB);
    if (part) {
        k_scale_pv<true><<<gB, 256, 0, stream>>>(pbuf, value, rowsum, attn, partials);
        k_reduce_out<<<dim3(4, NB), 256, 0, stream>>>(partials, out);
    } else {
        k_scale_pv<false><<<gB, 256, 0, stream>>>(pbuf, value, rowsum, attn, out);
    }
}